// Round 10
// baseline (214.205 us; speedup 1.0000x reference)
//
#include <hip/hip_runtime.h>
#include <hip/hip_bf16.h>

#define DEV __device__ __forceinline__

typedef __bf16 bf16x8 __attribute__((ext_vector_type(8)));
typedef float  f32x4  __attribute__((ext_vector_type(4)));

// caps = {512,1024,2048,4096,1024,512,2048,1024}
// 128-row-tile cumsum: {0,4,12,28,60,68,72,88,96}
// 256-row-tile cumsum: {0,2,6,14,30,34,36,44,48}

DEV unsigned short f2bf(float f) {
  union { float f; unsigned u; } v; v.f = f;
  unsigned u = v.u;
  return (unsigned short)((u + 0x7FFFu + ((u >> 16) & 1u)) >> 16);  // RNE
}

DEV float bf2f(unsigned short s) {
  union { unsigned u; float f; } v; v.u = (unsigned)s << 16; return v.f;
}

DEV void gld_lds16(const void* g, void* l) {
  __builtin_amdgcn_global_load_lds(
      (const __attribute__((address_space(1))) unsigned int*)g,
      (__attribute__((address_space(3))) unsigned int*)l, 16, 0, 0);
}

#define WAITVM(N) asm volatile("s_waitcnt vmcnt(" #N ")" ::: "memory"); \
                  __builtin_amdgcn_sched_barrier(0)
#define WAITLG(N) asm volatile("s_waitcnt lgkmcnt(" #N ")" ::: "memory"); \
                  __builtin_amdgcn_sched_barrier(0)
#define BARRIER() __builtin_amdgcn_s_barrier(); __builtin_amdgcn_sched_barrier(0)

// ---------------------------------------------------------------------------
// 256x256-tile 8-wave GEMM, m201-faithful PER-PHASE PACING.
// C = A @ B^T (+bias), optional split-K. BK=64, waves 2x4, wave-tile 128x64.
// LDS 128KB: A[2 gen][2 half][128x64] @0, B[...] @64KB.
// Round-10 theory: rounds 7-9 burst 12-16 frag reads per wave at tile top ->
// one ~1700cyc LDS storm + LDS-idle MFMA phases = serial (5540cyc/tile =
// 1700 LDS + 2483 MFMA + ovh). m201 paces <=12 reads/phase with a barrier
// sandwich around EVERY 16-MFMA cluster (8 barriers/tile) -> cross-wave
// stagger keeps LDS busy under MFMA (their MfmaUtil 62%).
// Phase layout per K-tile t (4 quadrants of wave-tile rows):
//  q0: stage a0(t+1); vmcnt(2) [retire tile t's 8 loads, keep a0(t+1)];
//      barrier; read B-frags(8)+A-sub0(4); lgkm(0); 16 MFMA; barrier
//  q1..q3: read A-subq(4) [pre-barrier: tile-t data protected by q0 barrier];
//      stage half q of t+1 (q1->a1,q2->b0,q3->b1); barrier; lgkm(0);
//      16 MFMA; barrier
// All stages target the opposite LDS generation; last reads of a generation
// complete at WAITLG before that tile's closing barriers -> no WAR barrier.
// vmcnt reaches 0 only at the last tile (T4).
// ---------------------------------------------------------------------------
template <int KT_, int KLEN, int SK, int N_, int NCT, bool OUT_BF16,
          bool HAS_BIAS, int EDIV>
__global__ __launch_bounds__(512, 2)
void gemm256q(const unsigned short* __restrict__ A,
              const unsigned short* __restrict__ B,
              const float* __restrict__ bias,
              void* __restrict__ C0, void* __restrict__ C1) {
  __shared__ __align__(128) char lds[131072];
  constexpr int NT = KLEN / 64;

  const int tid  = threadIdx.x;
  const int lane = tid & 63;
  const int wv   = tid >> 6;
  const int wm   = wv >> 2;      // 0..1  (128 out-rows)
  const int wn   = wv & 3;       // 0..3  (64 out-cols)
  const int fr   = lane & 15;
  const int fq   = lane >> 4;

  int bid = blockIdx.x;
  const int nwg = gridDim.x;
  bid = (bid & 7) * (nwg >> 3) + (bid >> 3);   // XCD swizzle (nwg % 8 == 0)

  int sk = 0;
  if constexpr (SK > 1) {
    const int per = nwg / SK;
    sk = bid / per;
    bid -= sk * per;
  }
  const int kStart = sk * KLEN;
  void* Cv = (SK > 1 && sk == 1) ? C1 : C0;

  const int rt = bid / NCT;
  const int ct = bid - rt * NCT;

  int e;
  if constexpr (EDIV > 0) {
    e = rt / EDIV;
  } else {
    const int cums[9] = {0, 2, 6, 14, 30, 34, 36, 44, 48};
    e = 0;
#pragma unroll
    for (int i = 1; i < 8; ++i) e += (rt >= cums[i]) ? 1 : 0;
  }

  const int grow0 = rt * 256;
  const int nloc0 = ct * 256;
  const unsigned short* Bg = B + (size_t)e * N_ * KT_;

  f32x4 acc[8][4];
#pragma unroll
  for (int i = 0; i < 8; ++i)
#pragma unroll
    for (int j = 0; j < 4; ++j) acc[i][j] = (f32x4){0.f, 0.f, 0.f, 0.f};

  // stage one 128x64 half-tile of K-tile t. h: 0,1 = A halves; 2,3 = B halves.
  // 2 gld_lds16/thread. LDS dest linear; global source pre-swizzled
  // (involution cb ^= (row&7)<<4) so frag reads are conflict-free.
  auto stage_half = [&](int t, int h) {
    const int kb = kStart + t * 64;
    char* dst = lds + (h >> 1) * 65536 + (t & 1) * 32768 + (h & 1) * 16384;
    const unsigned short* src = (h < 2) ? A : Bg;
    const int row0 = (h < 2) ? (grow0 + (h & 1) * 128) : (nloc0 + (h & 1) * 128);
#pragma unroll
    for (int s = 0; s < 2; ++s) {
      int o  = s * 8192 + wv * 1024 + lane * 16;
      int r  = o >> 7;
      int cb = (o & 127) ^ ((r & 7) << 4);
      gld_lds16(src + (size_t)(row0 + r) * KT_ + kb + (cb >> 1),
                dst + s * 8192 + wv * 1024);
    }
  };

  // prologue: tile 0 fully staged (8 loads outstanding)
  stage_half(0, 0); stage_half(0, 1); stage_half(0, 2); stage_half(0, 3);

  const int brow0 = (wn & 1) * 64;

  for (int t = 0; t < NT; ++t) {
    char* Ah = lds + (t & 1) * 32768 + wm * 16384;
    char* Bh = lds + 65536 + (t & 1) * 32768 + ((wn >> 1) * 16384);

    bf16x8 bfr[4][2], af[2][2];

    // ===== q0 =====
    if (t + 1 < NT) { stage_half(t + 1, 0); WAITVM(2); } else { WAITVM(0); }
    BARRIER();                       // tile t visible to ALL waves
#pragma unroll
    for (int ni = 0; ni < 4; ++ni) {
      int r = brow0 + ni * 16 + fr;
#pragma unroll
      for (int k = 0; k < 2; ++k)
        bfr[ni][k] = *(bf16x8*)(Bh + r * 128 + ((k * 64 + fq * 16) ^ ((r & 7) << 4)));
    }
#pragma unroll
    for (int j = 0; j < 2; ++j) {
      int r = j * 16 + fr;
#pragma unroll
      for (int k = 0; k < 2; ++k)
        af[j][k] = *(bf16x8*)(Ah + r * 128 + ((k * 64 + fq * 16) ^ ((r & 7) << 4)));
    }
    WAITLG(0);
    __builtin_amdgcn_s_setprio(1);
#pragma unroll
    for (int k = 0; k < 2; ++k)
#pragma unroll
      for (int j = 0; j < 2; ++j)
#pragma unroll
        for (int ni = 0; ni < 4; ++ni)
          acc[j][ni] = __builtin_amdgcn_mfma_f32_16x16x32_bf16(
              af[j][k], bfr[ni][k], acc[j][ni], 0, 0, 0);
    __builtin_amdgcn_s_setprio(0);
    BARRIER();

    // ===== q1..q3 =====
#pragma unroll
    for (int q = 1; q < 4; ++q) {
      // pre-barrier reads (tile-t data: landed, protected by q0 barrier)
#pragma unroll
      for (int j = 0; j < 2; ++j) {
        int r = (2 * q + j) * 16 + fr;
#pragma unroll
        for (int k = 0; k < 2; ++k)
          af[j][k] = *(bf16x8*)(Ah + r * 128 + ((k * 64 + fq * 16) ^ ((r & 7) << 4)));
      }
      if (t + 1 < NT) stage_half(t + 1, q);   // q1->a1, q2->b0, q3->b1
      BARRIER();
      WAITLG(0);
      __builtin_amdgcn_s_setprio(1);
#pragma unroll
      for (int k = 0; k < 2; ++k)
#pragma unroll
        for (int j = 0; j < 2; ++j)
#pragma unroll
          for (int ni = 0; ni < 4; ++ni)
            acc[2 * q + j][ni] = __builtin_amdgcn_mfma_f32_16x16x32_bf16(
                af[j][k], bfr[ni][k], acc[2 * q + j][ni], 0, 0, 0);
      __builtin_amdgcn_s_setprio(0);
      BARRIER();
    }
  }

  // epilogue: D layout col=lane&15 (n), row=(lane>>4)*4+reg (m)  [m89]
#pragma unroll
  for (int ni = 0; ni < 4; ++ni) {
    int ncol = nloc0 + wn * 64 + ni * 16 + fr;
    float bv = 0.f;
    if constexpr (HAS_BIAS) bv = (bias + (size_t)e * N_)[ncol];
#pragma unroll
    for (int mi = 0; mi < 8; ++mi) {
      int m = grow0 + wm * 128 + mi * 16 + fq * 4;
#pragma unroll
      for (int j = 0; j < 4; ++j) {
        float val = acc[mi][ni][j] + bv;
        if constexpr (OUT_BF16)
          ((unsigned short*)Cv)[(size_t)(m + j) * N_ + ncol] = f2bf(val);
        else
          ((float*)Cv)[(size_t)(m + j) * N_ + ncol] = val;
      }
    }
  }
}

// out[i] = bf16( f32(p0[i]) + f32(p1[i]) )  — split-K reduce
__global__ __launch_bounds__(256)
void reduce_bf16(const unsigned short* __restrict__ p0,
                 const unsigned short* __restrict__ p1,
                 unsigned short* __restrict__ out, int n8) {
  for (int i = blockIdx.x * 256 + threadIdx.x; i < n8; i += gridDim.x * 256) {
    ushort4 a0 = ((const ushort4*)p0)[2 * i];
    ushort4 a1 = ((const ushort4*)p0)[2 * i + 1];
    ushort4 b0 = ((const ushort4*)p1)[2 * i];
    ushort4 b1 = ((const ushort4*)p1)[2 * i + 1];
    ushort4 r0 = {f2bf(bf2f(a0.x) + bf2f(b0.x)), f2bf(bf2f(a0.y) + bf2f(b0.y)),
                  f2bf(bf2f(a0.z) + bf2f(b0.z)), f2bf(bf2f(a0.w) + bf2f(b0.w))};
    ushort4 r1 = {f2bf(bf2f(a1.x) + bf2f(b1.x)), f2bf(bf2f(a1.y) + bf2f(b1.y)),
                  f2bf(bf2f(a1.z) + bf2f(b1.z)), f2bf(bf2f(a1.w) + bf2f(b1.w))};
    ((ushort4*)out)[2 * i]     = r0;
    ((ushort4*)out)[2 * i + 1] = r1;
  }
}

// ---------------------------------------------------------------------------
// Proven fallback templates (low-ws paths only)
// ---------------------------------------------------------------------------
DEV int swz(int r, int cbyte) {
  return (r * 64 + cbyte) ^ (((r >> 1) & 7) << 4);
}

template <int K_, int N_, bool OUT_BF16, bool HAS_BIAS, int EDIV>
__global__ __launch_bounds__(512, 2)
void gemm8(const unsigned short* __restrict__ A,
           const unsigned short* __restrict__ B,
           const float* __restrict__ bias, void* __restrict__ Cv) {
  __shared__ __align__(128) char lds[2][49152];
  const int t    = threadIdx.x;
  const int lane = t & 63;
  const int wv   = t >> 6;
  const int wm   = wv >> 1;
  const int wn   = wv & 1;
  const int fr   = lane & 15;
  const int fq   = lane >> 4;
  constexpr int NCT = N_ / 128;
  constexpr int NT  = K_ / 64;

  int bid = blockIdx.x;
  const int nwg = gridDim.x;
  bid = (bid & 7) * (nwg >> 3) + (bid >> 3);
  const int rt = bid / NCT;
  const int ct = bid - rt * NCT;

  int e;
  if constexpr (EDIV > 0) {
    e = rt / EDIV;
  } else {
    const int cums[9] = {0, 2, 6, 14, 30, 34, 36, 44, 48};
    e = 0;
#pragma unroll
    for (int i = 1; i < 8; ++i) e += (rt >= cums[i]) ? 1 : 0;
  }

  const int grow0 = rt * 256;
  const int nloc0 = ct * 128;
  const unsigned short* Bg = B + (size_t)e * N_ * K_;

  f32x4 acc[4][4];
#pragma unroll
  for (int i = 0; i < 4; ++i)
#pragma unroll
    for (int j = 0; j < 4; ++j) acc[i][j] = (f32x4){0.f, 0.f, 0.f, 0.f};

  auto stage = [&](int buf, int tk) {
    const int kb = tk * 64;
    char* Abase = lds[buf];
    char* Bbase = lds[buf] + 32768;
#pragma unroll
    for (int s = 0; s < 4; ++s) {
      int o  = s * 8192 + wv * 1024 + lane * 16;
      int r  = o >> 7;
      int cb = (o & 127) ^ ((r & 7) << 4);
      gld_lds16(A + (size_t)(grow0 + r) * K_ + kb + (cb >> 1),
                Abase + s * 8192 + wv * 1024);
    }
#pragma unroll
    for (int s = 0; s < 2; ++s) {
      int o  = s * 8192 + wv * 1024 + lane * 16;
      int r  = o >> 7;
      int cb = (o & 127) ^ ((r & 7) << 4);
      gld_lds16(Bg + (size_t)(nloc0 + r) * K_ + kb + (cb >> 1),
                Bbase + s * 8192 + wv * 1024);
    }
  };

  auto compute = [&](int buf) {
    char* Abase = lds[buf];
    char* Bbase = lds[buf] + 32768;
    bf16x8 af[4][2], bf[4][2];
#pragma unroll
    for (int mi = 0; mi < 4; ++mi) {
      int r = wm * 64 + mi * 16 + fr;
#pragma unroll
      for (int k = 0; k < 2; ++k)
        af[mi][k] = *(bf16x8*)(Abase + r * 128 + ((k * 64 + fq * 16) ^ ((r & 7) << 4)));
    }
#pragma unroll
    for (int ni = 0; ni < 4; ++ni) {
      int r = wn * 64 + ni * 16 + fr;
#pragma unroll
      for (int k = 0; k < 2; ++k)
        bf[ni][k] = *(bf16x8*)(Bbase + r * 128 + ((k * 64 + fq * 16) ^ ((r & 7) << 4)));
    }
    __builtin_amdgcn_s_setprio(1);
#pragma unroll
    for (int k = 0; k < 2; ++k)
#pragma unroll
      for (int mi = 0; mi < 4; ++mi)
#pragma unroll
        for (int ni = 0; ni < 4; ++ni)
          acc[mi][ni] = __builtin_amdgcn_mfma_f32_16x16x32_bf16(
              af[mi][k], bf[ni][k], acc[mi][ni], 0, 0, 0);
    __builtin_amdgcn_s_setprio(0);
  };

  stage(0, 0);
  for (int tk = 0; tk < NT; ++tk) {
    const int cur = tk & 1;
    if (tk + 1 < NT) {
      stage(cur ^ 1, tk + 1);
      WAITVM(6);
    } else {
      WAITVM(0);
    }
    __builtin_amdgcn_s_barrier();
    compute(cur);
    WAITLG(0);
    __builtin_amdgcn_s_barrier();
  }

#pragma unroll
  for (int ni = 0; ni < 4; ++ni) {
    int nloc = nloc0 + wn * 64 + ni * 16 + fr;
    float bv = 0.f;
    if constexpr (HAS_BIAS) bv = (bias + (size_t)e * N_)[nloc];
#pragma unroll
    for (int mi = 0; mi < 4; ++mi) {
      int m = grow0 + wm * 64 + mi * 16 + fq * 4;
#pragma unroll
      for (int j = 0; j < 4; ++j) {
        float val = acc[mi][ni][j] + bv;
        if constexpr (OUT_BF16)
          ((unsigned short*)Cv)[(size_t)(m + j) * N_ + nloc] = f2bf(val);
        else
          ((float*)Cv)[(size_t)(m + j) * N_ + nloc] = val;
      }
    }
  }
}

template <int K_, int N_, int NCT_, bool OUT_BF16, bool HAS_BIAS, int EDIV>
__global__ __launch_bounds__(256)
void gemm_expert(const void* __restrict__ Av, const void* __restrict__ Bv,
                 const float* __restrict__ bias, void* __restrict__ Cv) {
  __shared__ char lds[2][12288];
  const int t    = threadIdx.x;
  const int lane = t & 63;
  const int wv   = t >> 6;
  const int wr   = wv >> 1;
  const int wc   = wv & 1;
  const int fr   = lane & 15;
  const int fq   = lane >> 4;

  int bid = blockIdx.x;
  const int nwg = gridDim.x;
  if ((nwg & 7) == 0) bid = (bid & 7) * (nwg >> 3) + (bid >> 3);
  const int rt = bid / NCT_;
  const int ct = bid - rt * NCT_;

  int e;
  if constexpr (EDIV > 0) {
    e = rt / EDIV;
  } else {
    const int cums[9] = {0, 4, 12, 28, 60, 68, 72, 88, 96};
    e = 0;
#pragma unroll
    for (int i = 1; i < 8; ++i) e += (rt >= cums[i]) ? 1 : 0;
  }

  const int grow0 = rt * 128;
  const int nloc0 = ct * 64;

  f32x4 acc[4][2];
#pragma unroll
  for (int i = 0; i < 4; ++i)
#pragma unroll
    for (int j = 0; j < 2; ++j) acc[i][j] = (f32x4){0.f, 0.f, 0.f, 0.f};

  const float* Af = (const float*)Av;
  const unsigned short* Bb = (const unsigned short*)Bv + (size_t)e * N_ * K_;

  auto stage = [&](int buf, int kb) {
    char* As = lds[buf];
    char* Bs = lds[buf] + 8192;
#pragma unroll
    for (int it = 0; it < 4; ++it) {
      int q = t + it * 256, r = q >> 3, c = (q & 7) * 4;
      float4 f = *(const float4*)(Af + (size_t)(grow0 + r) * K_ + kb + c);
      ushort4 v = {f2bf(f.x), f2bf(f.y), f2bf(f.z), f2bf(f.w)};
      *(ushort4*)(As + swz(r, c * 2)) = v;
    }
    int o = wv * 1024 + lane * 16;
    int p = o ^ (((o >> 7) & 7) << 4);
    gld_lds16(Bb + (size_t)(nloc0 + (p >> 6)) * K_ + kb + ((p & 63) >> 1),
              Bs + wv * 1024);
  };

  auto compute = [&](int buf) {
    char* As = lds[buf];
    char* Bs = lds[buf] + 8192;
    bf16x8 af[4], bfg[2];
#pragma unroll
    for (int mi = 0; mi < 4; ++mi)
      af[mi] = *(bf16x8*)(As + swz(wr * 64 + mi * 16 + fr, fq * 16));
#pragma unroll
    for (int ni = 0; ni < 2; ++ni)
      bfg[ni] = *(bf16x8*)(Bs + swz(wc * 32 + ni * 16 + fr, fq * 16));
#pragma unroll
    for (int mi = 0; mi < 4; ++mi)
#pragma unroll
      for (int ni = 0; ni < 2; ++ni)
        acc[mi][ni] = __builtin_amdgcn_mfma_f32_16x16x32_bf16(
            af[mi], bfg[ni], acc[mi][ni], 0, 0, 0);
  };

  int cur = 0;
  stage(0, 0);
  __syncthreads();
  for (int kb = 32; kb < K_; kb += 32) {
    stage(cur ^ 1, kb);
    compute(cur);
    __syncthreads();
    cur ^= 1;
  }
  compute(cur);

#pragma unroll
  for (int ni = 0; ni < 2; ++ni) {
    int nloc = nloc0 + wc * 32 + ni * 16 + fr;
    float bv = 0.f;
    if constexpr (HAS_BIAS) bv = (bias + (size_t)e * N_)[nloc];
#pragma unroll
    for (int mi = 0; mi < 4; ++mi) {
      int m = grow0 + wr * 64 + mi * 16 + fq * 4;
#pragma unroll
      for (int j = 0; j < 4; ++j) {
        float val = acc[mi][ni][j] + bv;
        if constexpr (OUT_BF16)
          ((unsigned short*)Cv)[(size_t)(m + j) * N_ + nloc] = f2bf(val);
        else
          ((float*)Cv)[(size_t)(m + j) * N_ + nloc] = val;
      }
    }
  }
}

// w1 (E,4096,1024) f32 -> w1t (E,1024,4096) bf16, 64x64 tiles via LDS
__global__ __launch_bounds__(256)
void transpose_w1(const float* __restrict__ w1, unsigned short* __restrict__ w1t) {
  __shared__ unsigned short tl[64 * 68];
  int b = blockIdx.x;
  int jt = b & 15, kt = (b >> 4) & 63, e = b >> 10;
  const float* src = w1 + ((size_t)e * 4096 + kt * 64) * 1024 + jt * 64;
  int t = threadIdx.x;
#pragma unroll
  for (int it = 0; it < 4; ++it) {
    int q = t + it * 256, kr = q >> 4, jc = (q & 15) * 4;
    float4 f = *(const float4*)(src + (size_t)kr * 1024 + jc);
    ushort4 v = {f2bf(f.x), f2bf(f.y), f2bf(f.z), f2bf(f.w)};
    *(ushort4*)&tl[kr * 68 + jc] = v;
  }
  __syncthreads();
  unsigned short* dst = w1t + ((size_t)e * 1024 + jt * 64) * 4096 + kt * 64;
#pragma unroll
  for (int it = 0; it < 4; ++it) {
    int q = t + it * 256, jr = q >> 4, kc = (q & 15) * 4;
    ushort4 v = {tl[(kc + 0) * 68 + jr], tl[(kc + 1) * 68 + jr],
                 tl[(kc + 2) * 68 + jr], tl[(kc + 3) * 68 + jr]};
    *(ushort4*)(dst + (size_t)jr * 4096 + kc) = v;
  }
}

template <bool STORE_BF>
__global__ __launch_bounds__(256)
void conv_w2_bias(const float* __restrict__ w2, const float* __restrict__ b1,
                  const float* __restrict__ b2, unsigned short* __restrict__ w2bf,
                  float* __restrict__ bc) {
  int row = blockIdx.x, e = row >> 10, t = threadIdx.x;
  const float* src = w2 + (size_t)row * 4096;
  const float* b1e = b1 + (size_t)e * 4096;
  float acc = 0.f;
#pragma unroll
  for (int it = 0; it < 4; ++it) {
    int c = (t + it * 256) * 4;
    float4 f = *(const float4*)(src + c);
    float4 g = *(const float4*)(b1e + c);
    acc += f.x * g.x + f.y * g.y + f.z * g.z + f.w * g.w;
    if constexpr (STORE_BF) {
      ushort4 v = {f2bf(f.x), f2bf(f.y), f2bf(f.z), f2bf(f.w)};
      *(ushort4*)(w2bf + (size_t)row * 4096 + c) = v;
    }
  }
#pragma unroll
  for (int o = 32; o > 0; o >>= 1) acc += __shfl_down(acc, o);
  __shared__ float red[4];
  if ((t & 63) == 0) red[t >> 6] = acc;
  __syncthreads();
  if (t == 0) bc[row] = red[0] + red[1] + red[2] + red[3] + b2[row];
}

__global__ __launch_bounds__(256)
void conv_f32_bf16(const float* __restrict__ in, unsigned short* __restrict__ out,
                   int n4) {
  for (int i = blockIdx.x * 256 + threadIdx.x; i < n4; i += gridDim.x * 256) {
    float4 f = *(const float4*)(in + (size_t)i * 4);
    ushort4 v = {f2bf(f.x), f2bf(f.y), f2bf(f.z), f2bf(f.w)};
    *(ushort4*)(out + (size_t)i * 4) = v;
  }
}

extern "C" void kernel_launch(void* const* d_in, const int* in_sizes, int n_in,
                              void* d_out, int out_size, void* d_ws, size_t ws_size,
                              hipStream_t stream) {
  const float* x  = (const float*)d_in[0];   // (12288, 1024)
  const float* w1 = (const float*)d_in[1];   // (8, 4096, 1024)
  const float* b1 = (const float*)d_in[2];   // (8, 4096)
  const float* w2 = (const float*)d_in[3];   // (8, 1024, 4096)
  const float* b2 = (const float*)d_in[4];   // (8, 1024)

  char* ws = (char*)d_ws;
  unsigned short* w1t = (unsigned short*)ws;              // 64 MiB
  const size_t NEED_T2 = 151126016, NEED_T3 = 176291840;

  if (ws_size >= NEED_T3) {
    unsigned short* w2bf = (unsigned short*)(ws + 67108864);   // 64 MiB
    unsigned short* Wc   = (unsigned short*)(ws + 134217728);  // 16 MiB (= SK p0)
    float*          bc   = (float*)(ws + 150994944);           // 32 KiB
    unsigned short* xbf  = (unsigned short*)(ws + 151126016);  // 25 MiB
    unsigned short* p1   = xbf;                                // 16 MiB, dead after reduce

    transpose_w1<<<8192, 256, 0, stream>>>(w1, w1t);
    conv_w2_bias<true><<<8192, 256, 0, stream>>>(w2, b1, b2, w2bf, bc);
    // Wc[e] = w2bf[e] @ w1t[e]^T : M=8192, N=1024, K=4096, split-K=2
    gemm256q<4096, 2048, 2, 1024, 4, true, false, 4>
        <<<256, 512, 0, stream>>>(w2bf, w1t, nullptr, Wc, p1);
    reduce_bf16<<<2048, 256, 0, stream>>>(Wc, p1, Wc, 8 * 1024 * 1024 / 8);
    conv_f32_bf16<<<2048, 256, 0, stream>>>(x, xbf, 12288 * 1024 / 4);
    // out = xbf @ Wc^T + bc : M=12288, N=1024, K=1024
    gemm256q<1024, 1024, 1, 1024, 4, false, true, 0>
        <<<192, 512, 0, stream>>>(xbf, Wc, bc, (float*)d_out, nullptr);
  } else if (ws_size >= NEED_T2) {
    unsigned short* w2bf = (unsigned short*)(ws + 67108864);
    unsigned short* Wc   = (unsigned short*)(ws + 134217728);
    float*          bc   = (float*)(ws + 150994944);

    transpose_w1<<<8192, 256, 0, stream>>>(w1, w1t);
    conv_w2_bias<true><<<8192, 256, 0, stream>>>(w2, b1, b2, w2bf, bc);
    gemm8<4096, 1024, true, false, 4>
        <<<256, 512, 0, stream>>>(w2bf, w1t, nullptr, Wc);
    gemm_expert<1024, 1024, 16, false, true, 0>
        <<<1536, 256, 0, stream>>>(x, Wc, bc, d_out);
  } else {
    // P2 fallback (84 MiB): f32-staged everywhere
    unsigned short* Wc = (unsigned short*)(ws + 67108864);
    float*          bc = (float*)(ws + 83886080);

    transpose_w1<<<8192, 256, 0, stream>>>(w1, w1t);
    conv_w2_bias<false><<<8192, 256, 0, stream>>>(w2, b1, b2, nullptr, bc);
    gemm_expert<4096, 1024, 8, true, false, 8>
        <<<768, 256, 0, stream>>>(w2, w1t, nullptr, Wc);
    gemm_expert<1024, 1024, 16, false, true, 0>
        <<<1536, 256, 0, stream>>>(x, Wc, bc, d_out);
  }
}

// Round 13
// 201.016 us; speedup vs baseline: 1.0656x; 1.0656x over previous
//
#include <hip/hip_runtime.h>
#include <hip/hip_bf16.h>

#define DEV __device__ __forceinline__

typedef __bf16 bf16x8 __attribute__((ext_vector_type(8)));
typedef float  f32x4  __attribute__((ext_vector_type(4)));

// caps = {512,1024,2048,4096,1024,512,2048,1024}
// 128-row-tile cumsum: {0,4,12,28,60,68,72,88,96}
// 256-row-tile cumsum: {0,2,6,14,30,34,36,44,48}

DEV unsigned short f2bf(float f) {
  union { float f; unsigned u; } v; v.f = f;
  unsigned u = v.u;
  return (unsigned short)((u + 0x7FFFu + ((u >> 16) & 1u)) >> 16);  // RNE
}

DEV float bf2f(unsigned short s) {
  union { unsigned u; float f; } v; v.u = (unsigned)s << 16; return v.f;
}

DEV void gld_lds16(const void* g, void* l) {
  __builtin_amdgcn_global_load_lds(
      (const __attribute__((address_space(1))) unsigned int*)g,
      (__attribute__((address_space(3))) unsigned int*)l, 16, 0, 0);
}

#define WAITVM(N) asm volatile("s_waitcnt vmcnt(" #N ")" ::: "memory"); \
                  __builtin_amdgcn_sched_barrier(0)
#define WAITLG(N) asm volatile("s_waitcnt lgkmcnt(" #N ")" ::: "memory"); \
                  __builtin_amdgcn_sched_barrier(0)
#define BARRIER() __builtin_amdgcn_s_barrier(); __builtin_amdgcn_sched_barrier(0)

// ---------------------------------------------------------------------------
// Wc GEMM (round-9 best, 931 TF = 2-phase structure ceiling): 256x256 tile,
// 8 waves 2x4, wave-tile 128x64, BK=64, 128KB LDS, counted vmcnt + register
// fragment pipeline (afX/afY lgkmcnt(4) rotation).
// ---------------------------------------------------------------------------
template <int KT_, int KLEN, int SK, int N_, int NCT, bool OUT_BF16,
          bool HAS_BIAS, int EDIV>
__global__ __launch_bounds__(512, 2)
void gemm256p(const unsigned short* __restrict__ A,
              const unsigned short* __restrict__ B,
              const float* __restrict__ bias,
              void* __restrict__ C0, void* __restrict__ C1) {
  __shared__ __align__(128) char lds[131072];
  constexpr int NT = KLEN / 64;

  const int tid  = threadIdx.x;
  const int lane = tid & 63;
  const int wv   = tid >> 6;
  const int wm   = wv >> 2;      // 0..1  (128 out-rows)
  const int wn   = wv & 3;       // 0..3  (64 out-cols)
  const int fr   = lane & 15;
  const int fq   = lane >> 4;

  int bid = blockIdx.x;
  const int nwg = gridDim.x;
  bid = (bid & 7) * (nwg >> 3) + (bid >> 3);   // XCD swizzle (nwg % 8 == 0)

  int sk = 0;
  if constexpr (SK > 1) {
    const int per = nwg / SK;
    sk = bid / per;
    bid -= sk * per;
  }
  const int kStart = sk * KLEN;
  void* Cv = (SK > 1 && sk == 1) ? C1 : C0;

  const int rt = bid / NCT;
  const int ct = bid - rt * NCT;

  int e;
  if constexpr (EDIV > 0) {
    e = rt / EDIV;
  } else {
    const int cums[9] = {0, 2, 6, 14, 30, 34, 36, 44, 48};
    e = 0;
#pragma unroll
    for (int i = 1; i < 8; ++i) e += (rt >= cums[i]) ? 1 : 0;
  }

  const int grow0 = rt * 256;
  const int nloc0 = ct * 256;
  const unsigned short* Bg = B + (size_t)e * N_ * KT_;

  f32x4 acc[8][4];
#pragma unroll
  for (int i = 0; i < 8; ++i)
#pragma unroll
    for (int j = 0; j < 4; ++j) acc[i][j] = (f32x4){0.f, 0.f, 0.f, 0.f};

  // stage one 128x64 half-tile of K-tile t. h: 0,1 = A halves; 2,3 = B halves.
  // LDS dest linear; global source pre-swizzled (cb ^= (row&7)<<4).
  auto stage_half = [&](int t, int h) {
    const int kb = kStart + t * 64;
    char* dst = lds + (h >> 1) * 65536 + (t & 1) * 32768 + (h & 1) * 16384;
    const unsigned short* src = (h < 2) ? A : Bg;
    const int row0 = (h < 2) ? (grow0 + (h & 1) * 128) : (nloc0 + (h & 1) * 128);
#pragma unroll
    for (int s = 0; s < 2; ++s) {
      int o  = s * 8192 + wv * 1024 + lane * 16;
      int r  = o >> 7;
      int cb = (o & 127) ^ ((r & 7) << 4);
      gld_lds16(src + (size_t)(row0 + r) * KT_ + kb + (cb >> 1),
                dst + s * 8192 + wv * 1024);
    }
  };

  // prologue. per-wave outstanding: a(0):4, b(0):4, b(1):4
  stage_half(0, 0); stage_half(0, 1); stage_half(0, 2); stage_half(0, 3);
  if constexpr (NT > 1) { stage_half(1, 2); stage_half(1, 3); }

  const int brow0 = (wn & 1) * 64;

  for (int t = 0; t < NT; ++t) {
    char* Ah = lds + (t & 1) * 32768 + wm * 16384;
    char* Bh = lds + 65536 + (t & 1) * 32768 + ((wn >> 1) * 16384);

    if (t + 1 < NT) { WAITVM(4); } else { WAITVM(0); }
    BARRIER();                       // RAW: tile t visible to ALL waves

    bf16x8 bfr[4][2], afX[2][2], afY[2][2];
#pragma unroll
    for (int ni = 0; ni < 4; ++ni) {
      int r = brow0 + ni * 16 + fr;
#pragma unroll
      for (int k = 0; k < 2; ++k)
        bfr[ni][k] = *(bf16x8*)(Bh + r * 128 + ((k * 64 + fq * 16) ^ ((r & 7) << 4)));
    }
#pragma unroll
    for (int j = 0; j < 2; ++j) {
      int r = j * 16 + fr;
#pragma unroll
      for (int k = 0; k < 2; ++k)
        afX[j][k] = *(bf16x8*)(Ah + r * 128 + ((k * 64 + fq * 16) ^ ((r & 7) << 4)));
    }
#pragma unroll
    for (int j = 0; j < 2; ++j) {
      int r = 32 + j * 16 + fr;
#pragma unroll
      for (int k = 0; k < 2; ++k)
        afY[j][k] = *(bf16x8*)(Ah + r * 128 + ((k * 64 + fq * 16) ^ ((r & 7) << 4)));
    }
    if (t + 1 < NT) stage_half(t + 1, 0);
    WAITLG(4);                       // B + A0 done; A1 outstanding
    BARRIER();                       // WAR: b-slot gen t&1 writable
    __builtin_amdgcn_s_setprio(1);
#pragma unroll
    for (int k = 0; k < 2; ++k)
#pragma unroll
      for (int j = 0; j < 2; ++j)
#pragma unroll
        for (int ni = 0; ni < 4; ++ni)
          acc[j][ni] = __builtin_amdgcn_mfma_f32_16x16x32_bf16(
              afX[j][k], bfr[ni][k], acc[j][ni], 0, 0, 0);
    __builtin_amdgcn_s_setprio(0);
#pragma unroll
    for (int j = 0; j < 2; ++j) {
      int r = 64 + j * 16 + fr;
#pragma unroll
      for (int k = 0; k < 2; ++k)
        afX[j][k] = *(bf16x8*)(Ah + r * 128 + ((k * 64 + fq * 16) ^ ((r & 7) << 4)));
    }
    if (t + 1 < NT) stage_half(t + 1, 1);
    if (t + 2 < NT) stage_half(t + 2, 2);
    WAITLG(4);                       // A1 done; A2 outstanding
    __builtin_amdgcn_s_setprio(1);
#pragma unroll
    for (int k = 0; k < 2; ++k)
#pragma unroll
      for (int j = 0; j < 2; ++j)
#pragma unroll
        for (int ni = 0; ni < 4; ++ni)
          acc[2 + j][ni] = __builtin_amdgcn_mfma_f32_16x16x32_bf16(
              afY[j][k], bfr[ni][k], acc[2 + j][ni], 0, 0, 0);
    __builtin_amdgcn_s_setprio(0);
#pragma unroll
    for (int j = 0; j < 2; ++j) {
      int r = 96 + j * 16 + fr;
#pragma unroll
      for (int k = 0; k < 2; ++k)
        afY[j][k] = *(bf16x8*)(Ah + r * 128 + ((k * 64 + fq * 16) ^ ((r & 7) << 4)));
    }
    if (t + 2 < NT) stage_half(t + 2, 3);
    WAITLG(4);                       // A2 done; A3 outstanding
    __builtin_amdgcn_s_setprio(1);
#pragma unroll
    for (int k = 0; k < 2; ++k)
#pragma unroll
      for (int j = 0; j < 2; ++j)
#pragma unroll
        for (int ni = 0; ni < 4; ++ni)
          acc[4 + j][ni] = __builtin_amdgcn_mfma_f32_16x16x32_bf16(
              afX[j][k], bfr[ni][k], acc[4 + j][ni], 0, 0, 0);
    __builtin_amdgcn_s_setprio(0);
    WAITLG(0);                       // A3 done
    __builtin_amdgcn_s_setprio(1);
#pragma unroll
    for (int k = 0; k < 2; ++k)
#pragma unroll
      for (int j = 0; j < 2; ++j)
#pragma unroll
        for (int ni = 0; ni < 4; ++ni)
          acc[6 + j][ni] = __builtin_amdgcn_mfma_f32_16x16x32_bf16(
              afY[j][k], bfr[ni][k], acc[6 + j][ni], 0, 0, 0);
    __builtin_amdgcn_s_setprio(0);
  }

  // epilogue: D layout col=lane&15 (n), row=(lane>>4)*4+reg (m)  [m89]
#pragma unroll
  for (int ni = 0; ni < 4; ++ni) {
    int ncol = nloc0 + wn * 64 + ni * 16 + fr;
    float bv = 0.f;
    if constexpr (HAS_BIAS) bv = (bias + (size_t)e * N_)[ncol];
#pragma unroll
    for (int mi = 0; mi < 8; ++mi) {
      int m = grow0 + wm * 128 + mi * 16 + fq * 4;
#pragma unroll
      for (int j = 0; j < 4; ++j) {
        float val = acc[mi][ni][j] + bv;
        if constexpr (OUT_BF16)
          ((unsigned short*)Cv)[(size_t)(m + j) * N_ + ncol] = f2bf(val);
        else
          ((float*)Cv)[(size_t)(m + j) * N_ + ncol] = val;
      }
    }
  }
}

// ---------------------------------------------------------------------------
// Final GEMM: 128x128 tile, 4 waves (2x2), wave-tile 64x64, BK=64,
// LDS 64KB dbuf -> 2 resident blocks/CU (async overlap, m97/m114 mechanism).
// Grid 96x8 = 768 blocks (round-10 diagnosis: old 256-tile final had grid
// 192 < 256 CUs -> quarter of machine idle -> 350 TF). Counted vmcnt(8).
// ---------------------------------------------------------------------------
template <int K_, int N_, int NCT, bool OUT_BF16, bool HAS_BIAS, int EDIV>
__global__ __launch_bounds__(256, 2)
void gemm128(const unsigned short* __restrict__ A,
             const unsigned short* __restrict__ B,
             const float* __restrict__ bias, void* __restrict__ Cv) {
  __shared__ __align__(128) char lds[2][32768];   // A 16KB + B 16KB per buf
  constexpr int NT = K_ / 64;

  const int tid  = threadIdx.x;
  const int lane = tid & 63;
  const int wv   = tid >> 6;     // 0..3
  const int wm   = wv >> 1;      // 0..1 (64 out-rows)
  const int wn   = wv & 1;       // 0..1 (64 out-cols)
  const int fr   = lane & 15;
  const int fq   = lane >> 4;

  int bid = blockIdx.x;
  const int nwg = gridDim.x;
  bid = (bid & 7) * (nwg >> 3) + (bid >> 3);   // XCD swizzle (nwg % 8 == 0)

  const int rt = bid / NCT;
  const int ct = bid - rt * NCT;

  int e;
  if constexpr (EDIV > 0) {
    e = rt / EDIV;
  } else {
    const int cums[9] = {0, 4, 12, 28, 60, 68, 72, 88, 96};
    e = 0;
#pragma unroll
    for (int i = 1; i < 8; ++i) e += (rt >= cums[i]) ? 1 : 0;
  }

  const int grow0 = rt * 128;
  const int nloc0 = ct * 128;
  const unsigned short* Bg = B + (size_t)e * N_ * K_;

  f32x4 acc[4][4];
#pragma unroll
  for (int i = 0; i < 4; ++i)
#pragma unroll
    for (int j = 0; j < 4; ++j) acc[i][j] = (f32x4){0.f, 0.f, 0.f, 0.f};

  // stage one full K-tile: A 128x64 + B 128x64 bf16 (8 gld_lds16/thread).
  // LDS dest linear; global source pre-swizzled (cb ^= (row&7)<<4).
  auto stage = [&](int buf, int tk) {
    const int kb = tk * 64;
#pragma unroll
    for (int s = 0; s < 4; ++s) {
      int o  = s * 4096 + wv * 1024 + lane * 16;
      int r  = o >> 7;
      int cb = (o & 127) ^ ((r & 7) << 4);
      gld_lds16(A + (size_t)(grow0 + r) * K_ + kb + (cb >> 1),
                lds[buf] + s * 4096 + wv * 1024);
    }
#pragma unroll
    for (int s = 0; s < 4; ++s) {
      int o  = s * 4096 + wv * 1024 + lane * 16;
      int r  = o >> 7;
      int cb = (o & 127) ^ ((r & 7) << 4);
      gld_lds16(Bg + (size_t)(nloc0 + r) * K_ + kb + (cb >> 1),
                lds[buf] + 16384 + s * 4096 + wv * 1024);
    }
  };

  stage(0, 0);
  for (int t = 0; t < NT; ++t) {
    const int cur = t & 1;
    if (t + 1 < NT) {
      stage(cur ^ 1, t + 1);   // 8 new loads; tile t's 8 still pending
      WAITVM(8);               // retire exactly tile t; t+1 stays in flight
    } else {
      WAITVM(0);
    }
    BARRIER();                 // tile t visible to all 4 waves

    char* Ab = lds[cur];
    char* Bb = lds[cur] + 16384;
    bf16x8 af[4][2], bf[4][2];
#pragma unroll
    for (int mi = 0; mi < 4; ++mi) {
      int r = wm * 64 + mi * 16 + fr;
#pragma unroll
      for (int k = 0; k < 2; ++k)
        af[mi][k] = *(bf16x8*)(Ab + r * 128 + ((k * 64 + fq * 16) ^ ((r & 7) << 4)));
    }
#pragma unroll
    for (int ni = 0; ni < 4; ++ni) {
      int r = wn * 64 + ni * 16 + fr;
#pragma unroll
      for (int k = 0; k < 2; ++k)
        bf[ni][k] = *(bf16x8*)(Bb + r * 128 + ((k * 64 + fq * 16) ^ ((r & 7) << 4)));
    }
    WAITLG(0);
    __builtin_amdgcn_s_setprio(1);
#pragma unroll
    for (int k = 0; k < 2; ++k)
#pragma unroll
      for (int mi = 0; mi < 4; ++mi)
#pragma unroll
        for (int ni = 0; ni < 4; ++ni)
          acc[mi][ni] = __builtin_amdgcn_mfma_f32_16x16x32_bf16(
              af[mi][k], bf[ni][k], acc[mi][ni], 0, 0, 0);
    __builtin_amdgcn_s_setprio(0);
    BARRIER();                 // all waves' reads done -> buf reusable
  }

  // epilogue: D layout col=lane&15 (n), row=(lane>>4)*4+reg (m)  [m89]
#pragma unroll
  for (int ni = 0; ni < 4; ++ni) {
    int ncol = nloc0 + wn * 64 + ni * 16 + fr;
    float bv = 0.f;
    if constexpr (HAS_BIAS) bv = (bias + (size_t)e * N_)[ncol];
#pragma unroll
    for (int mi = 0; mi < 4; ++mi) {
      int m = grow0 + wm * 64 + mi * 16 + fq * 4;
#pragma unroll
      for (int j = 0; j < 4; ++j) {
        float val = acc[mi][ni][j] + bv;
        if constexpr (OUT_BF16)
          ((unsigned short*)Cv)[(size_t)(m + j) * N_ + ncol] = f2bf(val);
        else
          ((float*)Cv)[(size_t)(m + j) * N_ + ncol] = val;
      }
    }
  }
}

// out[i] = bf16( f32(p0[i]) + f32(p1[i]) )  -- split-K reduce
__global__ __launch_bounds__(256)
void reduce_bf16(const unsigned short* __restrict__ p0,
                 const unsigned short* __restrict__ p1,
                 unsigned short* __restrict__ out, int n8) {
  for (int i = blockIdx.x * 256 + threadIdx.x; i < n8; i += gridDim.x * 256) {
    ushort4 a0 = ((const ushort4*)p0)[2 * i];
    ushort4 a1 = ((const ushort4*)p0)[2 * i + 1];
    ushort4 b0 = ((const ushort4*)p1)[2 * i];
    ushort4 b1 = ((const ushort4*)p1)[2 * i + 1];
    ushort4 r0 = {f2bf(bf2f(a0.x) + bf2f(b0.x)), f2bf(bf2f(a0.y) + bf2f(b0.y)),
                  f2bf(bf2f(a0.z) + bf2f(b0.z)), f2bf(bf2f(a0.w) + bf2f(b0.w))};
    ushort4 r1 = {f2bf(bf2f(a1.x) + bf2f(b1.x)), f2bf(bf2f(a1.y) + bf2f(b1.y)),
                  f2bf(bf2f(a1.z) + bf2f(b1.z)), f2bf(bf2f(a1.w) + bf2f(b1.w))};
    ((ushort4*)out)[2 * i]     = r0;
    ((ushort4*)out)[2 * i + 1] = r1;
  }
}

// ---------------------------------------------------------------------------
// Proven fallback templates (low-ws paths only)
// ---------------------------------------------------------------------------
DEV int swz(int r, int cbyte) {
  return (r * 64 + cbyte) ^ (((r >> 1) & 7) << 4);
}

template <int K_, int N_, bool OUT_BF16, bool HAS_BIAS, int EDIV>
__global__ __launch_bounds__(512, 2)
void gemm8(const unsigned short* __restrict__ A,
           const unsigned short* __restrict__ B,
           const float* __restrict__ bias, void* __restrict__ Cv) {
  __shared__ __align__(128) char lds[2][49152];
  const int t    = threadIdx.x;
  const int lane = t & 63;
  const int wv   = t >> 6;
  const int wm   = wv >> 1;
  const int wn   = wv & 1;
  const int fr   = lane & 15;
  const int fq   = lane >> 4;
  constexpr int NCT = N_ / 128;
  constexpr int NT  = K_ / 64;

  int bid = blockIdx.x;
  const int nwg = gridDim.x;
  bid = (bid & 7) * (nwg >> 3) + (bid >> 3);
  const int rt = bid / NCT;
  const int ct = bid - rt * NCT;

  int e;
  if constexpr (EDIV > 0) {
    e = rt / EDIV;
  } else {
    const int cums[9] = {0, 2, 6, 14, 30, 34, 36, 44, 48};
    e = 0;
#pragma unroll
    for (int i = 1; i < 8; ++i) e += (rt >= cums[i]) ? 1 : 0;
  }

  const int grow0 = rt * 256;
  const int nloc0 = ct * 128;
  const unsigned short* Bg = B + (size_t)e * N_ * K_;

  f32x4 acc[4][4];
#pragma unroll
  for (int i = 0; i < 4; ++i)
#pragma unroll
    for (int j = 0; j < 4; ++j) acc[i][j] = (f32x4){0.f, 0.f, 0.f, 0.f};

  auto stage = [&](int buf, int tk) {
    const int kb = tk * 64;
    char* Abase = lds[buf];
    char* Bbase = lds[buf] + 32768;
#pragma unroll
    for (int s = 0; s < 4; ++s) {
      int o  = s * 8192 + wv * 1024 + lane * 16;
      int r  = o >> 7;
      int cb = (o & 127) ^ ((r & 7) << 4);
      gld_lds16(A + (size_t)(grow0 + r) * K_ + kb + (cb >> 1),
                Abase + s * 8192 + wv * 1024);
    }
#pragma unroll
    for (int s = 0; s < 2; ++s) {
      int o  = s * 8192 + wv * 1024 + lane * 16;
      int r  = o >> 7;
      int cb = (o & 127) ^ ((r & 7) << 4);
      gld_lds16(Bg + (size_t)(nloc0 + r) * K_ + kb + (cb >> 1),
                Bbase + s * 8192 + wv * 1024);
    }
  };

  auto compute = [&](int buf) {
    char* Abase = lds[buf];
    char* Bbase = lds[buf] + 32768;
    bf16x8 af[4][2], bf[4][2];
#pragma unroll
    for (int mi = 0; mi < 4; ++mi) {
      int r = wm * 64 + mi * 16 + fr;
#pragma unroll
      for (int k = 0; k < 2; ++k)
        af[mi][k] = *(bf16x8*)(Abase + r * 128 + ((k * 64 + fq * 16) ^ ((r & 7) << 4)));
    }
#pragma unroll
    for (int ni = 0; ni < 4; ++ni) {
      int r = wn * 64 + ni * 16 + fr;
#pragma unroll
      for (int k = 0; k < 2; ++k)
        bf[ni][k] = *(bf16x8*)(Bbase + r * 128 + ((k * 64 + fq * 16) ^ ((r & 7) << 4)));
    }
    __builtin_amdgcn_s_setprio(1);
#pragma unroll
    for (int k = 0; k < 2; ++k)
#pragma unroll
      for (int mi = 0; mi < 4; ++mi)
#pragma unroll
        for (int ni = 0; ni < 4; ++ni)
          acc[mi][ni] = __builtin_amdgcn_mfma_f32_16x16x32_bf16(
              af[mi][k], bf[ni][k], acc[mi][ni], 0, 0, 0);
    __builtin_amdgcn_s_setprio(0);
  };

  stage(0, 0);
  for (int tk = 0; tk < NT; ++tk) {
    const int cur = tk & 1;
    if (tk + 1 < NT) {
      stage(cur ^ 1, tk + 1);
      WAITVM(6);
    } else {
      WAITVM(0);
    }
    __builtin_amdgcn_s_barrier();
    compute(cur);
    WAITLG(0);
    __builtin_amdgcn_s_barrier();
  }

#pragma unroll
  for (int ni = 0; ni < 4; ++ni) {
    int nloc = nloc0 + wn * 64 + ni * 16 + fr;
    float bv = 0.f;
    if constexpr (HAS_BIAS) bv = (bias + (size_t)e * N_)[nloc];
#pragma unroll
    for (int mi = 0; mi < 4; ++mi) {
      int m = grow0 + wm * 64 + mi * 16 + fq * 4;
#pragma unroll
      for (int j = 0; j < 4; ++j) {
        float val = acc[mi][ni][j] + bv;
        if constexpr (OUT_BF16)
          ((unsigned short*)Cv)[(size_t)(m + j) * N_ + nloc] = f2bf(val);
        else
          ((float*)Cv)[(size_t)(m + j) * N_ + nloc] = val;
      }
    }
  }
}

template <int K_, int N_, int NCT_, bool OUT_BF16, bool HAS_BIAS, int EDIV>
__global__ __launch_bounds__(256)
void gemm_expert(const void* __restrict__ Av, const void* __restrict__ Bv,
                 const float* __restrict__ bias, void* __restrict__ Cv) {
  __shared__ char lds[2][12288];
  const int t    = threadIdx.x;
  const int lane = t & 63;
  const int wv   = t >> 6;
  const int wr   = wv >> 1;
  const int wc   = wv & 1;
  const int fr   = lane & 15;
  const int fq   = lane >> 4;

  int bid = blockIdx.x;
  const int nwg = gridDim.x;
  if ((nwg & 7) == 0) bid = (bid & 7) * (nwg >> 3) + (bid >> 3);
  const int rt = bid / NCT_;
  const int ct = bid - rt * NCT_;

  int e;
  if constexpr (EDIV > 0) {
    e = rt / EDIV;
  } else {
    const int cums[9] = {0, 4, 12, 28, 60, 68, 72, 88, 96};
    e = 0;
#pragma unroll
    for (int i = 1; i < 8; ++i) e += (rt >= cums[i]) ? 1 : 0;
  }

  const int grow0 = rt * 128;
  const int nloc0 = ct * 64;

  f32x4 acc[4][2];
#pragma unroll
  for (int i = 0; i < 4; ++i)
#pragma unroll
    for (int j = 0; j < 2; ++j) acc[i][j] = (f32x4){0.f, 0.f, 0.f, 0.f};

  const float* Af = (const float*)Av;
  const unsigned short* Bb = (const unsigned short*)Bv + (size_t)e * N_ * K_;

  auto stage = [&](int buf, int kb) {
    char* As = lds[buf];
    char* Bs = lds[buf] + 8192;
#pragma unroll
    for (int it = 0; it < 4; ++it) {
      int q = t + it * 256, r = q >> 3, c = (q & 7) * 4;
      float4 f = *(const float4*)(Af + (size_t)(grow0 + r) * K_ + kb + c);
      ushort4 v = {f2bf(f.x), f2bf(f.y), f2bf(f.z), f2bf(f.w)};
      *(ushort4*)(As + swz(r, c * 2)) = v;
    }
    int o = wv * 1024 + lane * 16;
    int p = o ^ (((o >> 7) & 7) << 4);
    gld_lds16(Bb + (size_t)(nloc0 + (p >> 6)) * K_ + kb + ((p & 63) >> 1),
              Bs + wv * 1024);
  };

  auto compute = [&](int buf) {
    char* As = lds[buf];
    char* Bs = lds[buf] + 8192;
    bf16x8 af[4], bfg[2];
#pragma unroll
    for (int mi = 0; mi < 4; ++mi)
      af[mi] = *(bf16x8*)(As + swz(wr * 64 + mi * 16 + fr, fq * 16));
#pragma unroll
    for (int ni = 0; ni < 2; ++ni)
      bfg[ni] = *(bf16x8*)(Bs + swz(wc * 32 + ni * 16 + fr, fq * 16));
#pragma unroll
    for (int mi = 0; mi < 4; ++mi)
#pragma unroll
      for (int ni = 0; ni < 2; ++ni)
        acc[mi][ni] = __builtin_amdgcn_mfma_f32_16x16x32_bf16(
            af[mi], bfg[ni], acc[mi][ni], 0, 0, 0);
  };

  int cur = 0;
  stage(0, 0);
  __syncthreads();
  for (int kb = 32; kb < K_; kb += 32) {
    stage(cur ^ 1, kb);
    compute(cur);
    __syncthreads();
    cur ^= 1;
  }
  compute(cur);

#pragma unroll
  for (int ni = 0; ni < 2; ++ni) {
    int nloc = nloc0 + wc * 32 + ni * 16 + fr;
    float bv = 0.f;
    if constexpr (HAS_BIAS) bv = (bias + (size_t)e * N_)[nloc];
#pragma unroll
    for (int mi = 0; mi < 4; ++mi) {
      int m = grow0 + wr * 64 + mi * 16 + fq * 4;
#pragma unroll
      for (int j = 0; j < 4; ++j) {
        float val = acc[mi][ni][j] + bv;
        if constexpr (OUT_BF16)
          ((unsigned short*)Cv)[(size_t)(m + j) * N_ + nloc] = f2bf(val);
        else
          ((float*)Cv)[(size_t)(m + j) * N_ + nloc] = val;
      }
    }
  }
}

// w1 (E,4096,1024) f32 -> w1t (E,1024,4096) bf16, 64x64 tiles via LDS
__global__ __launch_bounds__(256)
void transpose_w1(const float* __restrict__ w1, unsigned short* __restrict__ w1t) {
  __shared__ unsigned short tl[64 * 68];
  int b = blockIdx.x;
  int jt = b & 15, kt = (b >> 4) & 63, e = b >> 10;
  const float* src = w1 + ((size_t)e * 4096 + kt * 64) * 1024 + jt * 64;
  int t = threadIdx.x;
#pragma unroll
  for (int it = 0; it < 4; ++it) {
    int q = t + it * 256, kr = q >> 4, jc = (q & 15) * 4;
    float4 f = *(const float4*)(src + (size_t)kr * 1024 + jc);
    ushort4 v = {f2bf(f.x), f2bf(f.y), f2bf(f.z), f2bf(f.w)};
    *(ushort4*)&tl[kr * 68 + jc] = v;
  }
  __syncthreads();
  unsigned short* dst = w1t + ((size_t)e * 1024 + jt * 64) * 4096 + kt * 64;
#pragma unroll
  for (int it = 0; it < 4; ++it) {
    int q = t + it * 256, jr = q >> 4, kc = (q & 15) * 4;
    ushort4 v = {tl[(kc + 0) * 68 + jr], tl[(kc + 1) * 68 + jr],
                 tl[(kc + 2) * 68 + jr], tl[(kc + 3) * 68 + jr]};
    *(ushort4*)(dst + (size_t)jr * 4096 + kc) = v;
  }
}

template <bool STORE_BF>
__global__ __launch_bounds__(256)
void conv_w2_bias(const float* __restrict__ w2, const float* __restrict__ b1,
                  const float* __restrict__ b2, unsigned short* __restrict__ w2bf,
                  float* __restrict__ bc) {
  int row = blockIdx.x, e = row >> 10, t = threadIdx.x;
  const float* src = w2 + (size_t)row * 4096;
  const float* b1e = b1 + (size_t)e * 4096;
  float acc = 0.f;
#pragma unroll
  for (int it = 0; it < 4; ++it) {
    int c = (t + it * 256) * 4;
    float4 f = *(const float4*)(src + c);
    float4 g = *(const float4*)(b1e + c);
    acc += f.x * g.x + f.y * g.y + f.z * g.z + f.w * g.w;
    if constexpr (STORE_BF) {
      ushort4 v = {f2bf(f.x), f2bf(f.y), f2bf(f.z), f2bf(f.w)};
      *(ushort4*)(w2bf + (size_t)row * 4096 + c) = v;
    }
  }
#pragma unroll
  for (int o = 32; o > 0; o >>= 1) acc += __shfl_down(acc, o);
  __shared__ float red[4];
  if ((t & 63) == 0) red[t >> 6] = acc;
  __syncthreads();
  if (t == 0) bc[row] = red[0] + red[1] + red[2] + red[3] + b2[row];
}

__global__ __launch_bounds__(256)
void conv_f32_bf16(const float* __restrict__ in, unsigned short* __restrict__ out,
                   int n4) {
  for (int i = blockIdx.x * 256 + threadIdx.x; i < n4; i += gridDim.x * 256) {
    float4 f = *(const float4*)(in + (size_t)i * 4);
    ushort4 v = {f2bf(f.x), f2bf(f.y), f2bf(f.z), f2bf(f.w)};
    *(ushort4*)(out + (size_t)i * 4) = v;
  }
}

extern "C" void kernel_launch(void* const* d_in, const int* in_sizes, int n_in,
                              void* d_out, int out_size, void* d_ws, size_t ws_size,
                              hipStream_t stream) {
  const float* x  = (const float*)d_in[0];   // (12288, 1024)
  const float* w1 = (const float*)d_in[1];   // (8, 4096, 1024)
  const float* b1 = (const float*)d_in[2];   // (8, 4096)
  const float* w2 = (const float*)d_in[3];   // (8, 1024, 4096)
  const float* b2 = (const float*)d_in[4];   // (8, 1024)

  char* ws = (char*)d_ws;
  unsigned short* w1t = (unsigned short*)ws;              // 64 MiB
  const size_t NEED_T2 = 151126016, NEED_T3 = 176291840;

  if (ws_size >= NEED_T3) {
    unsigned short* w2bf = (unsigned short*)(ws + 67108864);   // 64 MiB
    unsigned short* Wc   = (unsigned short*)(ws + 134217728);  // 16 MiB (= SK p0)
    float*          bc   = (float*)(ws + 150994944);           // 32 KiB
    unsigned short* xbf  = (unsigned short*)(ws + 151126016);  // 25 MiB
    unsigned short* p1   = xbf;                                // 16 MiB, dead after reduce

    transpose_w1<<<8192, 256, 0, stream>>>(w1, w1t);
    conv_w2_bias<true><<<8192, 256, 0, stream>>>(w2, b1, b2, w2bf, bc);
    // Wc[e] = w2bf[e] @ w1t[e]^T : M=8192, N=1024, K=4096, split-K=2
    gemm256p<4096, 2048, 2, 1024, 4, true, false, 4>
        <<<256, 512, 0, stream>>>(w2bf, w1t, nullptr, Wc, p1);
    reduce_bf16<<<2048, 256, 0, stream>>>(Wc, p1, Wc, 8 * 1024 * 1024 / 8);
    conv_f32_bf16<<<2048, 256, 0, stream>>>(x, xbf, 12288 * 1024 / 4);
    // out = xbf @ Wc^T + bc : M=12288, N=1024, K=1024 -- 128x128 tile,
    // grid 768, 2 blocks/CU (fixes the 192-block machine-underfill)
    gemm128<1024, 1024, 8, false, true, 0>
        <<<768, 256, 0, stream>>>(xbf, Wc, bc, (float*)d_out);
  } else if (ws_size >= NEED_T2) {
    unsigned short* w2bf = (unsigned short*)(ws + 67108864);
    unsigned short* Wc   = (unsigned short*)(ws + 134217728);
    float*          bc   = (float*)(ws + 150994944);

    transpose_w1<<<8192, 256, 0, stream>>>(w1, w1t);
    conv_w2_bias<true><<<8192, 256, 0, stream>>>(w2, b1, b2, w2bf, bc);
    gemm8<4096, 1024, true, false, 4>
        <<<256, 512, 0, stream>>>(w2bf, w1t, nullptr, Wc);
    gemm_expert<1024, 1024, 16, false, true, 0>
        <<<1536, 256, 0, stream>>>(x, Wc, bc, d_out);
  } else {
    // P2 fallback (84 MiB): f32-staged everywhere
    unsigned short* Wc = (unsigned short*)(ws + 67108864);
    float*          bc = (float*)(ws + 83886080);

    transpose_w1<<<8192, 256, 0, stream>>>(w1, w1t);
    conv_w2_bias<false><<<8192, 256, 0, stream>>>(w2, b1, b2, nullptr, bc);
    gemm_expert<4096, 1024, 8, true, false, 8>
        <<<768, 256, 0, stream>>>(w2, w1t, nullptr, Wc);
    gemm_expert<1024, 1024, 16, false, true, 0>
        <<<1536, 256, 0, stream>>>(x, Wc, bc, d_out);
  }
}